// Round 1
// baseline (43.299 us; speedup 1.0000x reference)
//
#include <hip/hip_runtime.h>
#include <hip/hip_bf16.h>
#include <math.h>

#define NS 512
#define OD 128
#define BB 64
#define TT 2000
#define KK 400
#define LOG2PI_F 1.8378770664093453f

// ws layout (floats):
//   [0,512)      row_lse
//   [512]        init_lse
//   [1024,1536)  A (softplus alpha + 1e-6)
//   [1536,2048)  B (softplus beta + 1e-6)
//   [2048,2560)  Dc = -lgamma(A) + A*log(B)
//   [2560,3072)  C0[s] = sum_d lv + 128*LOG2PI
//   [4096,4096+65536)   W[s][d] = exp(-lv)
//   ints at float offset 69632: frame_states[B*T]  (values are STATE ids)

__device__ __forceinline__ float softplusf(float x) {
    return (x > 20.f) ? x : log1pf(expf(x));
}

__global__ __launch_bounds__(256) void prep_kernel(
    const float* __restrict__ alpha_p, const float* __restrict__ beta_p,
    const float* __restrict__ trans, const float* __restrict__ init_logits,
    const float* __restrict__ logvars, float* __restrict__ ws)
{
    float* row_lse = ws;
    float* init_lse = ws + 512;
    float* As = ws + 1024;
    float* Bs = ws + 1536;
    float* Dc = ws + 2048;
    float* C0 = ws + 2560;
    float* W  = ws + 4096;

    __shared__ float red[4];
    const int tid = threadIdx.x;
    const int bid = blockIdx.x;

    if (bid < NS || bid == 1024) {
        // LSE over 512 elements (transition row, or initial logits)
        const float* src = (bid < NS) ? (trans + (size_t)bid * NS) : init_logits;
        float x0 = src[tid];
        float x1 = src[tid + 256];
        float m = fmaxf(x0, x1);
        for (int off = 32; off; off >>= 1) m = fmaxf(m, __shfl_down(m, off, 64));
        if ((tid & 63) == 0) red[tid >> 6] = m;
        __syncthreads();
        m = fmaxf(fmaxf(red[0], red[1]), fmaxf(red[2], red[3]));
        __syncthreads();
        float e = expf(x0 - m) + expf(x1 - m);
        for (int off = 32; off; off >>= 1) e += __shfl_down(e, off, 64);
        if ((tid & 63) == 0) red[tid >> 6] = e;
        __syncthreads();
        if (tid == 0) {
            float lse = m + logf(red[0] + red[1] + red[2] + red[3]);
            if (bid < NS) row_lse[bid] = lse;
            else         *init_lse = lse;
        }
    } else {
        // per-state tables: bid in [512,1024) -> state s
        const int s = bid - NS;
        float lv = 0.f;
        if (tid < OD) {
            lv = logvars[s * OD + tid];
            W[s * OD + tid] = expf(-lv);
        }
        float acc = lv;
        for (int off = 32; off; off >>= 1) acc += __shfl_down(acc, off, 64);
        if ((tid & 63) == 0) red[tid >> 6] = acc;
        __syncthreads();
        if (tid == 0) {
            C0[s] = red[0] + red[1] + red[2] + red[3] + OD * LOG2PI_F;
            float a = softplusf(alpha_p[s]) + 1e-6f;
            float b = softplusf(beta_p[s]) + 1e-6f;
            As[s] = a; Bs[s] = b;
            Dc[s] = -lgammaf(a) + a * logf(b);
        }
    }
}

__global__ __launch_bounds__(256) void seq_kernel(
    const int* __restrict__ states, const int* __restrict__ durs,
    const float* __restrict__ trans, const float* __restrict__ init_logits,
    const float* __restrict__ ws, int* __restrict__ fs, float* __restrict__ out)
{
    const float* row_lse = ws;
    const float* init_lse = ws + 512;
    const float* As = ws + 1024;
    const float* Bs = ws + 1536;
    const float* Dc = ws + 2048;

    __shared__ int st[KK];
    __shared__ int cum[512];
    __shared__ float red[4];

    const int b = blockIdx.x;
    const int tid = threadIdx.x;

    for (int k = tid; k < KK; k += 256) {
        st[k]  = states[b * KK + k];
        cum[k] = durs[b * KK + k];
    }
    for (int k = KK + tid; k < 512; k += 256) cum[k] = 0;
    __syncthreads();

    // Hillis-Steele inclusive scan over 512 (2 elems/thread)
    for (int off = 1; off < 512; off <<= 1) {
        const int i0 = tid, i1 = tid + 256;
        int v0 = (i0 >= off) ? cum[i0 - off] : 0;
        int v1 = (i1 >= off) ? cum[i1 - off] : 0;
        __syncthreads();
        cum[i0] += v0;
        cum[i1] += v1;
        __syncthreads();
    }
    // pad tail so binary search never exceeds 400
    for (int k = KK + tid; k < 512; k += 256) cum[k] = 0x7fffffff;
    __syncthreads();

    // frame -> state map via binary search (searchsorted side='right')
    for (int t = tid; t < TT; t += 256) {
        int lo = 0, hi = 512;
        while (lo < hi) {
            int mid = (lo + hi) >> 1;
            if (cum[mid] <= t) lo = mid + 1; else hi = mid;
        }
        int idx = (lo > KK - 1) ? (KK - 1) : lo;
        fs[b * TT + t] = st[idx];
    }

    // duration + transition log-probs
    float lp = 0.f;
    for (int k = tid; k < KK; k += 256) {
        const int s = st[k];
        const float d = (float)durs[b * KK + k];
        float v = (As[s] - 1.f) * logf(d + 1e-8f) - Bs[s] * d + Dc[s];
        lp += (d >= 1.f) ? v : -INFINITY;
        if (k < KK - 1) {
            const int sn = st[k + 1];
            lp += trans[(size_t)s * NS + sn] - row_lse[s];
        }
    }
    for (int off = 32; off; off >>= 1) lp += __shfl_down(lp, off, 64);
    if ((tid & 63) == 0) red[tid >> 6] = lp;
    __syncthreads();
    if (tid == 0) {
        float total = red[0] + red[1] + red[2] + red[3];
        out[b] = total + init_logits[st[0]] - *init_lse;
    }
}

__global__ __launch_bounds__(256) void obs_kernel(
    const float* __restrict__ obs, const float* __restrict__ mu,
    const float* __restrict__ ws, const int* __restrict__ fs,
    float* __restrict__ out)
{
    const float* C0 = ws + 2560;
    const float* W  = ws + 4096;

    const int b = blockIdx.x >> 5;       // 32 chunks per batch
    const int chunk = blockIdx.x & 31;
    const int t0 = chunk * 64;
    const int tid = threadIdx.x;
    const int row = tid >> 5;            // 0..7
    const int d = (tid & 31) * 4;

    float acc = 0.f;
    #pragma unroll
    for (int i = 0; i < 8; ++i) {
        const int t = t0 + i * 8 + row;
        if (t < TT) {
            const int s = fs[b * TT + t];
            const float4 o = *(const float4*)(obs + ((size_t)(b * TT + t)) * OD + d);
            const float4 m = *(const float4*)(mu + (size_t)s * OD + d);
            const float4 wv = *(const float4*)(W + (size_t)s * OD + d);
            const float dx = o.x - m.x, dy = o.y - m.y, dz = o.z - m.z, dw = o.w - m.w;
            acc += dx * dx * wv.x + dy * dy * wv.y + dz * dz * wv.z + dw * dw * wv.w;
            if ((tid & 31) == 0) acc += C0[s];
        }
    }
    for (int off = 32; off; off >>= 1) acc += __shfl_down(acc, off, 64);
    __shared__ float red[4];
    if ((tid & 63) == 0) red[tid >> 6] = acc;
    __syncthreads();
    if (tid == 0) atomicAdd(&out[b], -0.5f * (red[0] + red[1] + red[2] + red[3]));
}

extern "C" void kernel_launch(void* const* d_in, const int* in_sizes, int n_in,
                              void* d_out, int out_size, void* d_ws, size_t ws_size,
                              hipStream_t stream) {
    const float* observations = (const float*)d_in[0];
    const float* alpha_p      = (const float*)d_in[1];
    const float* beta_p       = (const float*)d_in[2];
    const float* trans        = (const float*)d_in[3];
    const float* init_logits  = (const float*)d_in[4];
    const float* obs_means    = (const float*)d_in[5];
    const float* obs_logvars  = (const float*)d_in[6];
    const int*   state_seq    = (const int*)d_in[7];
    const int*   dur_seq      = (const int*)d_in[8];

    float* ws = (float*)d_ws;
    int* fs = (int*)(ws + 69632);
    float* out = (float*)d_out;

    prep_kernel<<<1025, 256, 0, stream>>>(alpha_p, beta_p, trans, init_logits,
                                          obs_logvars, ws);
    seq_kernel<<<BB, 256, 0, stream>>>(state_seq, dur_seq, trans, init_logits,
                                       ws, fs, out);
    obs_kernel<<<BB * 32, 256, 0, stream>>>(observations, obs_means, ws, fs, out);
}

// Round 2
// 37.549 us; speedup vs baseline: 1.1531x; 1.1531x over previous
//
#include <hip/hip_runtime.h>
#include <hip/hip_bf16.h>
#include <math.h>

#define NS 512
#define OD 128
#define BB 64
#define TT 2000
#define KK 400
#define LOG2PI_F 1.8378770664093453f

// ws layout (floats):
//   [0,512)      row_lse
//   [512]        init_lse
//   [1024,1536)  A  = softplus(alpha)+1e-6
//   [1536,2048)  Bt = softplus(beta)+1e-6
//   [2048,2560)  Dc = A*log(Bt) - lgamma(A)
//   ints at ws+4096: frame_states[B*T] (state ids)

__device__ __forceinline__ float softplusf(float x) {
    return (x > 20.f) ? x : log1pf(expf(x));
}

__global__ __launch_bounds__(256) void k1_kernel(
    const float* __restrict__ alpha_p, const float* __restrict__ beta_p,
    const float* __restrict__ trans, const float* __restrict__ init_logits,
    const int* __restrict__ states, const int* __restrict__ durs,
    float* __restrict__ ws, int* __restrict__ fs, float* __restrict__ out)
{
    const int tid = threadIdx.x;
    const int bid = blockIdx.x;

    if (bid <= NS) {
        // LSE over 512 elems: transition row (bid<512) or initial logits (bid==512)
        __shared__ float red[4];
        const float* src = (bid < NS) ? (trans + (size_t)bid * NS) : init_logits;
        float x0 = src[tid];
        float x1 = src[tid + 256];
        float m = fmaxf(x0, x1);
        for (int off = 32; off; off >>= 1) m = fmaxf(m, __shfl_down(m, off, 64));
        if ((tid & 63) == 0) red[tid >> 6] = m;
        __syncthreads();
        m = fmaxf(fmaxf(red[0], red[1]), fmaxf(red[2], red[3]));
        __syncthreads();
        float e = __expf(x0 - m) + __expf(x1 - m);
        for (int off = 32; off; off >>= 1) e += __shfl_down(e, off, 64);
        if ((tid & 63) == 0) red[tid >> 6] = e;
        __syncthreads();
        if (tid == 0) {
            float lse = m + __logf(red[0] + red[1] + red[2] + red[3]);
            if (bid < NS) ws[bid] = lse;
            else         ws[512] = lse;
        }
        // a different wave computes this state's gamma-duration constants
        if (bid < NS && tid == 64) {
            float a = softplusf(alpha_p[bid]) + 1e-6f;
            float b = softplusf(beta_p[bid]) + 1e-6f;
            ws[1024 + bid] = a;
            ws[1536 + bid] = b;
            ws[2048 + bid] = a * __logf(b) - lgammaf(a);
        }
    } else {
        // frame->state map for batch b (no dependency on any table)
        const int b = bid - (NS + 1);
        __shared__ int st[KK];
        __shared__ int cum[512];
        for (int k = tid; k < KK; k += 256) {
            st[k]  = states[b * KK + k];
            cum[k] = durs[b * KK + k];
        }
        for (int k = KK + tid; k < 512; k += 256) cum[k] = 0;
        __syncthreads();
        for (int off = 1; off < 512; off <<= 1) {
            const int i0 = tid, i1 = tid + 256;
            int v0 = (i0 >= off) ? cum[i0 - off] : 0;
            int v1 = (i1 >= off) ? cum[i1 - off] : 0;
            __syncthreads();
            cum[i0] += v0;
            cum[i1] += v1;
            __syncthreads();
        }
        for (int k = KK + tid; k < 512; k += 256) cum[k] = 0x7fffffff;
        __syncthreads();
        for (int t = tid; t < TT; t += 256) {
            int lo = 0, hi = 512;
            while (lo < hi) {
                int mid = (lo + hi) >> 1;
                if (cum[mid] <= t) lo = mid + 1; else hi = mid;
            }
            int idx = (lo > KK - 1) ? (KK - 1) : lo;
            fs[b * TT + t] = st[idx];
        }
        if (tid == 0) out[b] = 0.f;
    }
}

__global__ __launch_bounds__(256) void k2_kernel(
    const float* __restrict__ obs, const float* __restrict__ mu,
    const float* __restrict__ lvar, const float* __restrict__ trans,
    const float* __restrict__ init_logits,
    const int* __restrict__ states, const int* __restrict__ durs,
    const float* __restrict__ ws, const int* __restrict__ fs,
    float* __restrict__ out)
{
    const int tid = threadIdx.x;
    const int bid = blockIdx.x;
    __shared__ float red[4];

    if (bid < BB * 32) {
        // observation log-prob, 64 frames per block, exp(-lv) on the fly
        const int b = bid >> 5;
        const int chunk = bid & 31;
        const int t0 = chunk * 64;
        const int row = tid >> 5;          // 0..7
        const int d = (tid & 31) * 4;

        float acc = 0.f;
        #pragma unroll
        for (int i = 0; i < 8; ++i) {
            const int t = t0 + i * 8 + row;
            if (t < TT) {
                const int s = fs[b * TT + t];
                const float4 o  = *(const float4*)(obs + ((size_t)(b * TT + t)) * OD + d);
                const float4 m  = *(const float4*)(mu  + (size_t)s * OD + d);
                const float4 lv = *(const float4*)(lvar + (size_t)s * OD + d);
                const float dx = o.x - m.x, dy = o.y - m.y, dz = o.z - m.z, dw = o.w - m.w;
                acc += lv.x + lv.y + lv.z + lv.w + 4.f * LOG2PI_F
                     + dx * dx * __expf(-lv.x) + dy * dy * __expf(-lv.y)
                     + dz * dz * __expf(-lv.z) + dw * dw * __expf(-lv.w);
            }
        }
        for (int off = 32; off; off >>= 1) acc += __shfl_down(acc, off, 64);
        if ((tid & 63) == 0) red[tid >> 6] = acc;
        __syncthreads();
        if (tid == 0) atomicAdd(&out[b], -0.5f * (red[0] + red[1] + red[2] + red[3]));
    } else {
        // duration + transition + init log-probs for batch b
        const int b = bid - BB * 32;
        __shared__ int st[KK];
        for (int k = tid; k < KK; k += 256) st[k] = states[b * KK + k];
        __syncthreads();
        float lp = 0.f;
        for (int k = tid; k < KK; k += 256) {
            const int s = st[k];
            const float dv = (float)durs[b * KK + k];
            const float a = ws[1024 + s];
            const float bt = ws[1536 + s];
            float v = (a - 1.f) * __logf(dv + 1e-8f) - bt * dv + ws[2048 + s];
            lp += (dv >= 1.f) ? v : -INFINITY;
            if (k < KK - 1) lp += trans[(size_t)s * NS + st[k + 1]] - ws[s];
        }
        for (int off = 32; off; off >>= 1) lp += __shfl_down(lp, off, 64);
        if ((tid & 63) == 0) red[tid >> 6] = lp;
        __syncthreads();
        if (tid == 0)
            atomicAdd(&out[b], red[0] + red[1] + red[2] + red[3]
                               + init_logits[st[0]] - ws[512]);
    }
}

extern "C" void kernel_launch(void* const* d_in, const int* in_sizes, int n_in,
                              void* d_out, int out_size, void* d_ws, size_t ws_size,
                              hipStream_t stream) {
    const float* observations = (const float*)d_in[0];
    const float* alpha_p      = (const float*)d_in[1];
    const float* beta_p       = (const float*)d_in[2];
    const float* trans        = (const float*)d_in[3];
    const float* init_logits  = (const float*)d_in[4];
    const float* obs_means    = (const float*)d_in[5];
    const float* obs_logvars  = (const float*)d_in[6];
    const int*   state_seq    = (const int*)d_in[7];
    const int*   dur_seq      = (const int*)d_in[8];

    float* ws = (float*)d_ws;
    int* fs = (int*)(ws + 4096);
    float* out = (float*)d_out;

    k1_kernel<<<NS + 1 + BB, 256, 0, stream>>>(alpha_p, beta_p, trans, init_logits,
                                               state_seq, dur_seq, ws, fs, out);
    k2_kernel<<<BB * 32 + BB, 256, 0, stream>>>(observations, obs_means, obs_logvars,
                                                trans, init_logits, state_seq, dur_seq,
                                                ws, fs, out);
}

// Round 3
// 26.024 us; speedup vs baseline: 1.6638x; 1.4428x over previous
//
#include <hip/hip_runtime.h>
#include <hip/hip_bf16.h>
#include <math.h>

#define NS 512
#define OD 128
#define BB 64
#define TT 2000
#define KK 400
#define CHUNK 128
#define NCH 16            // ceil(2000/128)
#define LOG2PI_F 1.8378770664093453f
#define PART_OFF 4096     // ws float offset of per-block partials [BB*NCH]

// ws layout (floats):
//   [0,512)    row_lse (transition log-softmax denominators)
//   [512]      init_lse
//   [4096,4096+1024)  obs partial sums, one per (b,chunk)

__device__ __forceinline__ float softplusf(float x) {
    return (x > 20.f) ? x : log1pf(expf(x));
}

__global__ __launch_bounds__(256) void big_kernel(
    const float* __restrict__ obs, const float* __restrict__ mu,
    const float* __restrict__ lvar, const float* __restrict__ trans,
    const float* __restrict__ init_logits,
    const int* __restrict__ states, const int* __restrict__ durs,
    float* __restrict__ ws)
{
    const int tid = threadIdx.x;
    const int bid = blockIdx.x;
    __shared__ float red[4];

    if (bid < BB * NCH) {
        // ---- observation partial for (batch b, frame chunk) ----
        const int b = bid >> 4;
        const int chunk = bid & 15;
        const int t0 = chunk * CHUNK;

        __shared__ int st[KK];
        __shared__ int cum[512];
        __shared__ int fsl[CHUNK];

        for (int k = tid; k < KK; k += 256) {
            st[k]  = states[b * KK + k];
            cum[k] = durs[b * KK + k];
        }
        for (int k = KK + tid; k < 512; k += 256) cum[k] = 0;
        __syncthreads();
        // inclusive scan over 512 (2 elems/thread, Hillis-Steele)
        for (int off = 1; off < 512; off <<= 1) {
            const int i0 = tid, i1 = tid + 256;
            int v0 = (i0 >= off) ? cum[i0 - off] : 0;
            int v1 = (i1 >= off) ? cum[i1 - off] : 0;
            __syncthreads();
            cum[i0] += v0;
            cum[i1] += v1;
            __syncthreads();
        }
        for (int k = KK + tid; k < 512; k += 256) cum[k] = 0x7fffffff;
        __syncthreads();
        // frame->state for this chunk only (searchsorted side='right')
        if (tid < CHUNK) {
            const int t = t0 + tid;
            int lo = 0, hi = 512;
            while (lo < hi) {
                int mid = (lo + hi) >> 1;
                if (cum[mid] <= t) lo = mid + 1; else hi = mid;
            }
            fsl[tid] = st[(lo > KK - 1) ? (KK - 1) : lo];
        }
        __syncthreads();

        const int row = tid >> 5;          // 0..7 frames per iter
        const int d = (tid & 31) * 4;
        float acc = 0.f;
        #pragma unroll
        for (int i = 0; i < CHUNK / 8; ++i) {
            const int t = t0 + i * 8 + row;
            if (t < TT) {
                const int s = fsl[i * 8 + row];
                const float4 o  = *(const float4*)(obs + ((size_t)(b * TT + t)) * OD + d);
                const float4 m  = *(const float4*)(mu  + (size_t)s * OD + d);
                const float4 lv = *(const float4*)(lvar + (size_t)s * OD + d);
                const float dx = o.x - m.x, dy = o.y - m.y, dz = o.z - m.z, dw = o.w - m.w;
                acc += lv.x + lv.y + lv.z + lv.w + 4.f * LOG2PI_F
                     + dx * dx * __expf(-lv.x) + dy * dy * __expf(-lv.y)
                     + dz * dz * __expf(-lv.z) + dw * dw * __expf(-lv.w);
            }
        }
        for (int off = 32; off; off >>= 1) acc += __shfl_down(acc, off, 64);
        if ((tid & 63) == 0) red[tid >> 6] = acc;
        __syncthreads();
        if (tid == 0)
            ws[PART_OFF + bid] = red[0] + red[1] + red[2] + red[3];
    } else {
        // ---- LSE blocks: transition rows (r<512) or initial logits (r==512) ----
        const int r = bid - BB * NCH;
        const float* src = (r < NS) ? (trans + (size_t)r * NS) : init_logits;
        float x0 = src[tid];
        float x1 = src[tid + 256];
        float m = fmaxf(x0, x1);
        for (int off = 32; off; off >>= 1) m = fmaxf(m, __shfl_down(m, off, 64));
        if ((tid & 63) == 0) red[tid >> 6] = m;
        __syncthreads();
        m = fmaxf(fmaxf(red[0], red[1]), fmaxf(red[2], red[3]));
        __syncthreads();
        float e = __expf(x0 - m) + __expf(x1 - m);
        for (int off = 32; off; off >>= 1) e += __shfl_down(e, off, 64);
        if ((tid & 63) == 0) red[tid >> 6] = e;
        __syncthreads();
        if (tid == 0) {
            float lse = m + __logf(red[0] + red[1] + red[2] + red[3]);
            ws[(r < NS) ? r : 512] = lse;
        }
    }
}

__global__ __launch_bounds__(256) void fin_kernel(
    const float* __restrict__ alpha_p, const float* __restrict__ beta_p,
    const float* __restrict__ trans, const float* __restrict__ init_logits,
    const int* __restrict__ states, const int* __restrict__ durs,
    const float* __restrict__ ws, float* __restrict__ out)
{
    const int b = blockIdx.x;
    const int tid = threadIdx.x;
    __shared__ float red[4];

    float lp = 0.f;
    if (tid < NCH) lp = -0.5f * ws[PART_OFF + b * NCH + tid];

    for (int k = tid; k < KK; k += 256) {
        const int s = states[b * KK + k];
        const float dv = (float)durs[b * KK + k];
        const float a  = softplusf(alpha_p[s]) + 1e-6f;
        const float bt = softplusf(beta_p[s]) + 1e-6f;
        float v = (a - 1.f) * __logf(dv + 1e-8f) - bt * dv + a * __logf(bt) - lgammaf(a);
        lp += (dv >= 1.f) ? v : -INFINITY;
        if (k < KK - 1)
            lp += trans[(size_t)s * NS + states[b * KK + k + 1]] - ws[s];
    }
    for (int off = 32; off; off >>= 1) lp += __shfl_down(lp, off, 64);
    if ((tid & 63) == 0) red[tid >> 6] = lp;
    __syncthreads();
    if (tid == 0)
        out[b] = red[0] + red[1] + red[2] + red[3]
               + init_logits[states[b * KK]] - ws[512];
}

extern "C" void kernel_launch(void* const* d_in, const int* in_sizes, int n_in,
                              void* d_out, int out_size, void* d_ws, size_t ws_size,
                              hipStream_t stream) {
    const float* observations = (const float*)d_in[0];
    const float* alpha_p      = (const float*)d_in[1];
    const float* beta_p       = (const float*)d_in[2];
    const float* trans        = (const float*)d_in[3];
    const float* init_logits  = (const float*)d_in[4];
    const float* obs_means    = (const float*)d_in[5];
    const float* obs_logvars  = (const float*)d_in[6];
    const int*   state_seq    = (const int*)d_in[7];
    const int*   dur_seq      = (const int*)d_in[8];

    float* ws = (float*)d_ws;
    float* out = (float*)d_out;

    big_kernel<<<BB * NCH + NS + 1, 256, 0, stream>>>(
        observations, obs_means, obs_logvars, trans, init_logits,
        state_seq, dur_seq, ws);
    fin_kernel<<<BB, 256, 0, stream>>>(
        alpha_p, beta_p, trans, init_logits, state_seq, dur_seq, ws, out);
}

// Round 4
// 22.212 us; speedup vs baseline: 1.9494x; 1.1716x over previous
//
#include <hip/hip_runtime.h>
#include <hip/hip_bf16.h>
#include <math.h>

#define NS 512
#define OD 128
#define BB 64
#define TT 2000
#define KK 400
#define CHUNK 128
#define NCH 16            // 2000/128 rounded up
#define LOG2PI_F 1.8378770664093453f
#define PART_OFF 4096     // ws float offset: obs partials [BB*NCH]
#define SEQ_OFF  5632     // ws float offset: seq partials [BB]

// ws layout (floats):
//   [0,512)    row_lse        [512] init_lse
//   [PART_OFF, +1024)  obs partial sums (one per b,chunk)
//   [SEQ_OFF, +64)     duration + transition-numerator partials per batch

__device__ __forceinline__ float softplusf(float x) {
    return (x > 20.f) ? x : log1pf(expf(x));
}

// grid: [0, BB*NCH) obs | [BB*NCH, +NS+1) lse | [BB*NCH+NS+1, +BB) seq
__global__ __launch_bounds__(256) void big_kernel(
    const float* __restrict__ obs, const float* __restrict__ mu,
    const float* __restrict__ lvar, const float* __restrict__ trans,
    const float* __restrict__ init_logits,
    const float* __restrict__ alpha_p, const float* __restrict__ beta_p,
    const int* __restrict__ states, const int* __restrict__ durs,
    float* __restrict__ ws)
{
    const int tid = threadIdx.x;
    const int bid = blockIdx.x;
    __shared__ float red[4];

    if (bid < BB * NCH) {
        // ---- observation partial for (batch b, 128-frame chunk) ----
        const int b = bid >> 4;
        const int t0 = (bid & 15) * CHUNK;

        __shared__ int st[KK];
        __shared__ int cum[512];
        __shared__ int csum[8];
        __shared__ int fsl[CHUNK];

        // load states + durations; wave-shuffle inclusive scan of durations
        const int lane = tid & 63, w = tid >> 6;
        int v0 = 0, v1 = 0;
        if (tid < KK) { st[tid] = states[b * KK + tid]; v0 = durs[b * KK + tid]; }
        if (tid + 256 < KK) { st[tid + 256] = states[b * KK + tid + 256];
                              v1 = durs[b * KK + tid + 256]; }
        #pragma unroll
        for (int off = 1; off < 64; off <<= 1) {
            int u0 = __shfl_up(v0, off, 64);
            int u1 = __shfl_up(v1, off, 64);
            if (lane >= off) { v0 += u0; v1 += u1; }
        }
        if (lane == 63) { csum[w] = v0; csum[4 + w] = v1; }
        __syncthreads();
        int off0 = 0, off1 = 0;
        #pragma unroll
        for (int c = 0; c < 8; ++c) {
            int cs = csum[c];
            off0 += (c < w) ? cs : 0;
            off1 += (c < 4 + w) ? cs : 0;
        }
        cum[tid] = v0 + off0;
        cum[tid + 256] = v1 + off1;   // k>=400 holds total (harmless for side-right)
        __syncthreads();

        // frame->state for this chunk (searchsorted side='right', clip to K-1)
        if (tid < CHUNK) {
            const int t = t0 + tid;
            int lo = 0, hi = KK;       // cum[399]=total > any t<total; t>=total -> lo=KK
            while (lo < hi) {
                int mid = (lo + hi) >> 1;
                if (cum[mid] <= t) lo = mid + 1; else hi = mid;
            }
            fsl[tid] = st[(lo > KK - 1) ? (KK - 1) : lo];
        }
        __syncthreads();

        const int row = tid >> 5;          // 8 frames per iter
        const int d = (tid & 31) * 4;
        float acc = 0.f;
        #pragma unroll
        for (int i = 0; i < CHUNK / 8; ++i) {
            const int t = t0 + i * 8 + row;
            if (t < TT) {
                const int s = fsl[i * 8 + row];
                const float4 o  = *(const float4*)(obs + ((size_t)(b * TT + t)) * OD + d);
                const float4 m  = *(const float4*)(mu  + (size_t)s * OD + d);
                const float4 lv = *(const float4*)(lvar + (size_t)s * OD + d);
                const float dx = o.x - m.x, dy = o.y - m.y, dz = o.z - m.z, dw = o.w - m.w;
                acc += lv.x + lv.y + lv.z + lv.w + 4.f * LOG2PI_F
                     + dx * dx * __expf(-lv.x) + dy * dy * __expf(-lv.y)
                     + dz * dz * __expf(-lv.z) + dw * dw * __expf(-lv.w);
            }
        }
        for (int off = 32; off; off >>= 1) acc += __shfl_down(acc, off, 64);
        if ((tid & 63) == 0) red[tid >> 6] = acc;
        __syncthreads();
        if (tid == 0)
            ws[PART_OFF + bid] = red[0] + red[1] + red[2] + red[3];
    } else if (bid < BB * NCH + NS + 1) {
        // ---- LSE: transition row r<512, or initial logits (r==512) ----
        const int r = bid - BB * NCH;
        const float* src = (r < NS) ? (trans + (size_t)r * NS) : init_logits;
        float x0 = src[tid];
        float x1 = src[tid + 256];
        float m = fmaxf(x0, x1);
        for (int off = 32; off; off >>= 1) m = fmaxf(m, __shfl_down(m, off, 64));
        if ((tid & 63) == 0) red[tid >> 6] = m;
        __syncthreads();
        m = fmaxf(fmaxf(red[0], red[1]), fmaxf(red[2], red[3]));
        __syncthreads();
        float e = __expf(x0 - m) + __expf(x1 - m);
        for (int off = 32; off; off >>= 1) e += __shfl_down(e, off, 64);
        if ((tid & 63) == 0) red[tid >> 6] = e;
        __syncthreads();
        if (tid == 0)
            ws[(r < NS) ? r : 512] = m + __logf(red[0] + red[1] + red[2] + red[3]);
    } else {
        // ---- seq: duration terms + transition NUMERATOR (lse subtracted in fin) ----
        const int b = bid - (BB * NCH + NS + 1);
        float lp = 0.f;
        for (int k = tid; k < KK; k += 256) {
            const int s = states[b * KK + k];
            const float dv = (float)durs[b * KK + k];
            const float a  = softplusf(alpha_p[s]) + 1e-6f;
            const float bt = softplusf(beta_p[s]) + 1e-6f;
            float v = (a - 1.f) * __logf(dv + 1e-8f) - bt * dv
                    + a * __logf(bt) - lgammaf(a);
            lp += (dv >= 1.f) ? v : -INFINITY;
            if (k < KK - 1)
                lp += trans[(size_t)s * NS + states[b * KK + k + 1]];
        }
        for (int off = 32; off; off >>= 1) lp += __shfl_down(lp, off, 64);
        if ((tid & 63) == 0) red[tid >> 6] = lp;
        __syncthreads();
        if (tid == 0)
            ws[SEQ_OFF + b] = red[0] + red[1] + red[2] + red[3];
    }
}

__global__ __launch_bounds__(256) void fin_kernel(
    const float* __restrict__ init_logits, const int* __restrict__ states,
    const float* __restrict__ ws, float* __restrict__ out)
{
    const int b = blockIdx.x;
    const int tid = threadIdx.x;
    __shared__ float red[4];

    float lp = 0.f;
    if (tid < NCH)        lp = -0.5f * ws[PART_OFF + b * NCH + tid];
    else if (tid == NCH)  lp = ws[SEQ_OFF + b];
    // subtract row_lse for each transition (2 KB table, L1-hot)
    for (int k = tid; k < KK - 1; k += 256)
        lp -= ws[states[b * KK + k]];
    for (int off = 32; off; off >>= 1) lp += __shfl_down(lp, off, 64);
    if ((tid & 63) == 0) red[tid >> 6] = lp;
    __syncthreads();
    if (tid == 0)
        out[b] = red[0] + red[1] + red[2] + red[3]
               + init_logits[states[b * KK]] - ws[512];
}

extern "C" void kernel_launch(void* const* d_in, const int* in_sizes, int n_in,
                              void* d_out, int out_size, void* d_ws, size_t ws_size,
                              hipStream_t stream) {
    const float* observations = (const float*)d_in[0];
    const float* alpha_p      = (const float*)d_in[1];
    const float* beta_p       = (const float*)d_in[2];
    const float* trans        = (const float*)d_in[3];
    const float* init_logits  = (const float*)d_in[4];
    const float* obs_means    = (const float*)d_in[5];
    const float* obs_logvars  = (const float*)d_in[6];
    const int*   state_seq    = (const int*)d_in[7];
    const int*   dur_seq      = (const int*)d_in[8];

    float* ws = (float*)d_ws;
    float* out = (float*)d_out;

    big_kernel<<<BB * NCH + NS + 1 + BB, 256, 0, stream>>>(
        observations, obs_means, obs_logvars, trans, init_logits,
        alpha_p, beta_p, state_seq, dur_seq, ws);
    fin_kernel<<<BB, 256, 0, stream>>>(init_logits, state_seq, ws, out);
}